// Round 3
// baseline (538.602 us; speedup 1.0000x reference)
//
#include <hip/hip_runtime.h>
#include <hip/hip_bf16.h>
#include <cstdint>

#define FEAT    128
#define NRBF    20
#define NATOMS  8192
#define NEDGES  262144
#define NGRAPH  128
#define APG     64
#define PI_F    3.14159265358979323846f
#define CUTOFF_F 5.0f

typedef unsigned int uint_t;
typedef unsigned short ushort_t;
typedef __attribute__((ext_vector_type(4))) float f32x4;
typedef __attribute__((ext_vector_type(8))) short short8;

__device__ __forceinline__ float bflo(uint_t u) { return __uint_as_float(u << 16); }
__device__ __forceinline__ float bfhi(uint_t u) { return __uint_as_float(u & 0xffff0000u); }
__device__ __forceinline__ ushort_t f2bf(float f) {
  uint_t u = __float_as_uint(f);
  return (ushort_t)((u + 0x7fffu + ((u >> 16) & 1u)) >> 16);
}
__device__ __forceinline__ float pick4(float a0, float a1, float a2, float a3, int g) {
  return (g == 0) ? a0 : (g == 1) ? a1 : (g == 2) ? a2 : a3;
}

// ---------------------------------------------------------------- GEMM (K=128)
// mode: 0 = f32 out, 1 = f32 out + SiLU, 2 = bf16 out
__global__ __launch_bounds__(256) void gemm_k128(
    const float* __restrict__ A, const float* __restrict__ W,
    const float* __restrict__ bias, float* __restrict__ Cf,
    ushort_t* __restrict__ Cb, int N, int mode) {
  __shared__ float As[64][132];
  __shared__ float Ws[128][68];
  const int r0 = blockIdx.x * 64;
  const int c0 = blockIdx.y * 64;
  const int t = threadIdx.x;

  {
    const float* Abase = A + (size_t)r0 * 128;
    for (int i = t; i < 64 * 32; i += 256) {
      int r = i >> 5, k4 = i & 31;
      float4 v = *reinterpret_cast<const float4*>(Abase + r * 128 + k4 * 4);
      *reinterpret_cast<float4*>(&As[r][k4 * 4]) = v;
    }
  }
  {
    for (int i = t; i < 128 * 16; i += 256) {
      int k = i >> 4, c4 = i & 15;
      float4 v = *reinterpret_cast<const float4*>(W + (size_t)k * N + c0 + c4 * 4);
      *reinterpret_cast<float4*>(&Ws[k][c4 * 4]) = v;
    }
  }
  __syncthreads();

  const int tx = t & 15, ty = t >> 4;
  float acc[4][4] = {};
  #pragma unroll 4
  for (int k4 = 0; k4 < 32; ++k4) {
    float4 a0 = *reinterpret_cast<const float4*>(&As[ty * 4 + 0][4 * k4]);
    float4 a1 = *reinterpret_cast<const float4*>(&As[ty * 4 + 1][4 * k4]);
    float4 a2 = *reinterpret_cast<const float4*>(&As[ty * 4 + 2][4 * k4]);
    float4 a3 = *reinterpret_cast<const float4*>(&As[ty * 4 + 3][4 * k4]);
    float4 w0 = *reinterpret_cast<const float4*>(&Ws[4 * k4 + 0][tx * 4]);
    float4 w1 = *reinterpret_cast<const float4*>(&Ws[4 * k4 + 1][tx * 4]);
    float4 w2 = *reinterpret_cast<const float4*>(&Ws[4 * k4 + 2][tx * 4]);
    float4 w3 = *reinterpret_cast<const float4*>(&Ws[4 * k4 + 3][tx * 4]);
    #define UPD(i, av)                                              \
      acc[i][0] += av.x*w0.x + av.y*w1.x + av.z*w2.x + av.w*w3.x;   \
      acc[i][1] += av.x*w0.y + av.y*w1.y + av.z*w2.y + av.w*w3.y;   \
      acc[i][2] += av.x*w0.z + av.y*w1.z + av.z*w2.z + av.w*w3.z;   \
      acc[i][3] += av.x*w0.w + av.y*w1.w + av.z*w2.w + av.w*w3.w;
    UPD(0, a0) UPD(1, a1) UPD(2, a2) UPD(3, a3)
    #undef UPD
  }

  float4 bb = *reinterpret_cast<const float4*>(bias + c0 + tx * 4);
  #pragma unroll
  for (int i = 0; i < 4; ++i) {
    float o0 = acc[i][0] + bb.x;
    float o1 = acc[i][1] + bb.y;
    float o2 = acc[i][2] + bb.z;
    float o3 = acc[i][3] + bb.w;
    if (mode == 1) {
      o0 = o0 / (1.f + __expf(-o0));
      o1 = o1 / (1.f + __expf(-o1));
      o2 = o2 / (1.f + __expf(-o2));
      o3 = o3 / (1.f + __expf(-o3));
    }
    size_t off = (size_t)(r0 + ty * 4 + i) * N + c0 + tx * 4;
    if (mode == 2) {
      ushort4 ov = {f2bf(o0), f2bf(o1), f2bf(o2), f2bf(o3)};
      *reinterpret_cast<ushort4*>(Cb + off) = ov;
    } else {
      float4 ov = {o0, o1, o2, o3};
      *reinterpret_cast<float4*>(Cf + off) = ov;
    }
  }
}

// ------------------------------------------------- v_j repack: [j][f][c] f32 -> [j][c][f] bf16
__global__ void repackv_kernel(const float* __restrict__ in, ushort_t* __restrict__ out) {
  int i = blockIdx.x * 256 + threadIdx.x;
  int j = i / 384, rem = i - j * 384;
  int c = rem >> 7, f = rem & 127;
  out[i] = f2bf(in[(size_t)j * 384 + f * 3 + c]);
}

// ---------------------------------------------------------------- sort helpers
__global__ void zero_kernel(int* __restrict__ p, int n) {
  int i = blockIdx.x * blockDim.x + threadIdx.x;
  if (i < n) p[i] = 0;
}

__global__ void hist_kernel(const int* __restrict__ nbrs, int* __restrict__ counts) {
  int e = blockIdx.x * blockDim.x + threadIdx.x;
  if (e < NEDGES) atomicAdd(&counts[nbrs[2 * e]], 1);
}

__global__ __launch_bounds__(1024) void scan_kernel(
    const int* __restrict__ counts, int* __restrict__ offs, int* __restrict__ cursor) {
  __shared__ int part[1024];
  const int t = threadIdx.x;
  int local[8];
  int s = 0;
  #pragma unroll
  for (int i = 0; i < 8; ++i) { local[i] = counts[t * 8 + i]; s += local[i]; }
  part[t] = s;
  __syncthreads();
  for (int off = 1; off < 1024; off <<= 1) {
    int v = part[t];
    int add = (t >= off) ? part[t - off] : 0;
    __syncthreads();
    part[t] = v + add;
    __syncthreads();
  }
  int excl = part[t] - s;
  #pragma unroll
  for (int i = 0; i < 8; ++i) {
    offs[t * 8 + i] = excl;
    cursor[t * 8 + i] = excl;
    excl += local[i];
  }
  if (t == 1023) offs[NATOMS] = excl;
}

__global__ void scatter_kernel(const int* __restrict__ nbrs, int* __restrict__ cursor,
                               int* __restrict__ sorted) {
  int e = blockIdx.x * blockDim.x + threadIdx.x;
  if (e < NEDGES) {
    int seg = nbrs[2 * e];
    int pos = atomicAdd(&cursor[seg], 1);
    sorted[pos] = e;
  }
}

// ---------------------------------------------------------------- edge MFMA kernel
// One wave per atom. Per 16-edge tile: A = (env/d)*sin((k+1)*c1*d) [16 x 32pad] bf16
// (lane q = l&15 owns edge eb+q's row; K padded 20->32, same k(g,j) map on A and B so
// the K permutation cancels). B = Wr [32pad x 16] bf16, columns permuted so lane's
// feat pair (2q, 2q+1) of tile-pair (h=0,1) is one aligned b32 gather of phi/v.
// C (m89-verified): col = l&15 = feat, row = 4*(l>>4)+reg = edge. env*br folds into
// C-init. Lane reduces over its 4 edge-rows in-register; 2 xor-shuffles per acc at end.
__global__ __launch_bounds__(256) void edge_mfma_kernel(
    const int* __restrict__ sorted, const int* __restrict__ offs,
    const int* __restrict__ nbrs, const float* __restrict__ r_ij,
    const ushort_t* __restrict__ phi, const ushort_t* __restrict__ vbf,
    const float* __restrict__ Wr, const float* __restrict__ br,
    float* __restrict__ out_s, float* __restrict__ out_v) {
  __shared__ short8 sWrB8[24 * 64];
  __shared__ float sBr[384];
  short* sWrB = (short*)sWrB8;
  const int t = threadIdx.x;

  // stage Wr fragments: sWrB[nt][lane][jj] = bf16(Wr[k(g,jj)][f(nt,q)]), 0 if k>=20
  for (int i = t; i < 24 * 64 * 8; i += 256) {
    int jj = i & 7, lane = (i >> 3) & 63, nt = i >> 9;
    int g = lane >> 4, q = lane & 15;
    int s = nt >> 3, ft = nt & 7, nt8 = ft & 3, h = ft >> 2;
    int k = 4 * g + (jj & 3) + 16 * (jj >> 2);
    int f = s * 128 + 32 * nt8 + 2 * q + h;
    sWrB[i] = (k < NRBF) ? (short)f2bf(Wr[k * 384 + f]) : (short)0;
  }
  for (int i = t; i < 384; i += 256) {
    int nt = i >> 4, q = i & 15;
    int s = nt >> 3, ft = nt & 7, nt8 = ft & 3, h = ft >> 2;
    sBr[i] = br[s * 128 + 32 * nt8 + 2 * q + h];
  }
  __syncthreads();

  const int w = t >> 6, l = t & 63, g = l >> 4, q = l & 15;
  const int atom = blockIdx.x * 4 + w;
  const int start = offs[atom], end = offs[atom + 1];
  const float c1 = PI_F / CUTOFF_F;

  float ds_acc[4][2] = {};     // [nt8][h]
  float dv_acc[4][2][3] = {};  // [nt8][h][c]

  for (int eb = start; eb < end; eb += 16) {
    // ---- per-edge metadata: lane handles edge eb+q (replicated across groups)
    float ang = 0.f, ie = 0.f, envv = 0.f, u0 = 0.f, u1 = 0.f, u2 = 0.f;
    int jn = 0;
    if (eb + q < end) {
      int e = sorted[eb + q];
      float x = r_ij[3 * e], y = r_ij[3 * e + 1], z = r_ij[3 * e + 2];
      jn = nbrs[2 * e + 1];
      float d = sqrtf(x * x + y * y + z * z);
      float inv = 1.f / d;
      ang = c1 * d;
      envv = (d < CUTOFF_F) ? 0.5f * (__cosf(ang) + 1.f) : 0.f;
      ie = inv * envv;
      u0 = x * inv; u1 = y * inv; u2 = z * inv;
    }
    // ---- A fragment (8 bf16): sv(k) = ie * sin((k+1)*ang), k = 4g+(jj&3)+16*(jj>>2)
    short8 afrag;
    #pragma unroll
    for (int jj = 0; jj < 8; ++jj) {
      int k = 4 * g + (jj & 3) + 16 * (jj >> 2);
      float sv = (k < NRBF) ? ie * __sinf((float)(k + 1) * ang) : 0.f;
      afrag[jj] = (short)f2bf(sv);
    }
    // ---- row metadata via bpermute: row r <-> edge eb + 4g + r
    float envb[4], ub0[4], ub1[4], ub2[4];
    const ushort_t *pb[4], *vb[4];
    #pragma unroll
    for (int r = 0; r < 4; ++r) {
      int src = 4 * g + r;
      int jr = __shfl(jn, src, 64);
      envb[r] = __shfl(envv, src, 64);
      ub0[r] = __shfl(u0, src, 64);
      ub1[r] = __shfl(u1, src, 64);
      ub2[r] = __shfl(u2, src, 64);
      pb[r] = phi + (size_t)jr * 384 + 2 * q;
      vb[r] = vbf + (size_t)jr * 384 + 2 * q;
    }
    // ---- 12 (s,nt8) steps; phi/v gathers double-buffered one step ahead
    uint_t ph[2][4], vv[2][4][3];
    #pragma unroll
    for (int r = 0; r < 4; ++r) {
      ph[0][r] = *(const uint_t*)(pb[r]);
      vv[0][r][0] = *(const uint_t*)(vb[r]);
      vv[0][r][1] = *(const uint_t*)(vb[r] + 128);
      vv[0][r][2] = *(const uint_t*)(vb[r] + 256);
    }
    #pragma unroll
    for (int snt = 0; snt < 12; ++snt) {
      const int cur = snt & 1;
      const int s = snt >> 2, nt8 = snt & 3;
      if (snt < 11) {
        const int s2 = (snt + 1) >> 2, n2 = (snt + 1) & 3;
        #pragma unroll
        for (int r = 0; r < 4; ++r) {
          ph[cur ^ 1][r] = *(const uint_t*)(pb[r] + s2 * 128 + 32 * n2);
          if (s2 == 0) {
            vv[cur ^ 1][r][0] = *(const uint_t*)(vb[r] + 32 * n2);
            vv[cur ^ 1][r][1] = *(const uint_t*)(vb[r] + 128 + 32 * n2);
            vv[cur ^ 1][r][2] = *(const uint_t*)(vb[r] + 256 + 32 * n2);
          }
        }
      }
      short8 b0 = sWrB8[(s * 8 + nt8) * 64 + l];
      short8 b1 = sWrB8[(s * 8 + nt8 + 4) * 64 + l];
      float brv0 = sBr[(s * 8 + nt8) * 16 + q];
      float brv1 = sBr[(s * 8 + nt8 + 4) * 16 + q];
      f32x4 c0, c1;
      #pragma unroll
      for (int r = 0; r < 4; ++r) { c0[r] = envb[r] * brv0; c1[r] = envb[r] * brv1; }
      c0 = __builtin_amdgcn_mfma_f32_16x16x32_bf16(afrag, b0, c0, 0, 0, 0);
      c1 = __builtin_amdgcn_mfma_f32_16x16x32_bf16(afrag, b1, c1, 0, 0, 0);
      #pragma unroll
      for (int r = 0; r < 4; ++r) {
        uint_t pp = ph[cur][r];
        float p0 = bflo(pp), p1 = bfhi(pp);
        if (s == 1) {
          ds_acc[nt8][0] += p0 * c0[r];
          ds_acc[nt8][1] += p1 * c1[r];
        } else if (s == 0) {
          float pw0 = p0 * c0[r], pw1 = p1 * c1[r];
          uint_t v0 = vv[cur][r][0], v1 = vv[cur][r][1], v2 = vv[cur][r][2];
          dv_acc[nt8][0][0] += pw0 * bflo(v0);
          dv_acc[nt8][1][0] += pw1 * bfhi(v0);
          dv_acc[nt8][0][1] += pw0 * bflo(v1);
          dv_acc[nt8][1][1] += pw1 * bfhi(v1);
          dv_acc[nt8][0][2] += pw0 * bflo(v2);
          dv_acc[nt8][1][2] += pw1 * bfhi(v2);
        } else {
          float pw0 = p0 * c0[r], pw1 = p1 * c1[r];
          dv_acc[nt8][0][0] += pw0 * ub0[r];
          dv_acc[nt8][1][0] += pw1 * ub0[r];
          dv_acc[nt8][0][1] += pw0 * ub1[r];
          dv_acc[nt8][1][1] += pw1 * ub1[r];
          dv_acc[nt8][0][2] += pw0 * ub2[r];
          dv_acc[nt8][1][2] += pw1 * ub2[r];
        }
      }
    }
  }

  // ---- cross-group reduce; lane (g,q) writes feats 32g+2q+{0,1}
  #pragma unroll
  for (int nt8 = 0; nt8 < 4; ++nt8) {
    #pragma unroll
    for (int h = 0; h < 2; ++h) {
      float x = ds_acc[nt8][h];
      x += __shfl_xor(x, 16, 64); x += __shfl_xor(x, 32, 64);
      ds_acc[nt8][h] = x;
      #pragma unroll
      for (int c = 0; c < 3; ++c) {
        float y = dv_acc[nt8][h][c];
        y += __shfl_xor(y, 16, 64); y += __shfl_xor(y, 32, 64);
        dv_acc[nt8][h][c] = y;
      }
    }
  }
  int fb = 32 * g + 2 * q;
  float s0 = pick4(ds_acc[0][0], ds_acc[1][0], ds_acc[2][0], ds_acc[3][0], g);
  float s1 = pick4(ds_acc[0][1], ds_acc[1][1], ds_acc[2][1], ds_acc[3][1], g);
  *reinterpret_cast<float2*>(out_s + (size_t)atom * FEAT + fb) = make_float2(s0, s1);
  float d00 = pick4(dv_acc[0][0][0], dv_acc[1][0][0], dv_acc[2][0][0], dv_acc[3][0][0], g);
  float d01 = pick4(dv_acc[0][0][1], dv_acc[1][0][1], dv_acc[2][0][1], dv_acc[3][0][1], g);
  float d02 = pick4(dv_acc[0][0][2], dv_acc[1][0][2], dv_acc[2][0][2], dv_acc[3][0][2], g);
  float d10 = pick4(dv_acc[0][1][0], dv_acc[1][1][0], dv_acc[2][1][0], dv_acc[3][1][0], g);
  float d11 = pick4(dv_acc[0][1][1], dv_acc[1][1][1], dv_acc[2][1][1], dv_acc[3][1][1], g);
  float d12 = pick4(dv_acc[0][1][2], dv_acc[1][1][2], dv_acc[2][1][2], dv_acc[3][1][2], g);
  float* ov = out_v + (size_t)atom * 384 + (size_t)fb * 3;
  *reinterpret_cast<float2*>(ov + 0) = make_float2(d00, d01);
  *reinterpret_cast<float2*>(ov + 2) = make_float2(d02, d10);
  *reinterpret_cast<float2*>(ov + 4) = make_float2(d11, d12);
}

// ---------------------------------------------------------------- attention
__device__ __forceinline__ float wave_max64(float v) {
  #pragma unroll
  for (int m = 32; m > 0; m >>= 1) v = fmaxf(v, __shfl_xor(v, m, 64));
  return v;
}
__device__ __forceinline__ float wave_sum64(float v) {
  #pragma unroll
  for (int m = 32; m > 0; m >>= 1) v += __shfl_xor(v, m, 64);
  return v;
}

__global__ __launch_bounds__(256) void attn_kernel(const float* __restrict__ qkv,
                                                   float* __restrict__ out_s) {
  __shared__ float4 Ks4[64 * 32];
  __shared__ float  Vs[64][130];
  __shared__ float  Ps[4][4][64];
  const int b = blockIdx.x;
  const int t = threadIdx.x;
  const float* base = qkv + (size_t)b * APG * 384;

  for (int i = t; i < 64 * 32; i += 256) {
    int a = i >> 5, gg = i & 31;
    float4 kv = *reinterpret_cast<const float4*>(base + a * 384 + 128 + 4 * gg);
    Ks4[a * 32 + (gg ^ (a & 7))] = kv;
  }
  for (int i = t; i < 64 * 32; i += 256) {
    int a = i >> 5, gg = i & 31;
    float4 vvv = *reinterpret_cast<const float4*>(base + a * 384 + 256 + 4 * gg);
    Vs[a][4 * gg + 0] = vvv.x; Vs[a][4 * gg + 1] = vvv.y;
    Vs[a][4 * gg + 2] = vvv.z; Vs[a][4 * gg + 3] = vvv.w;
  }
  __syncthreads();

  const int w = t >> 6, l = t & 63;
  const float scale = 0.08838834764831845f;

  for (int qq = w; qq < 16; qq += 4) {
    const float* q0p = base + (size_t)(4 * qq + 0) * 384;
    const float* q1p = base + (size_t)(4 * qq + 1) * 384;
    const float* q2p = base + (size_t)(4 * qq + 2) * 384;
    const float* q3p = base + (size_t)(4 * qq + 3) * 384;
    float s0 = 0.f, s1 = 0.f, s2 = 0.f, s3 = 0.f;
    #pragma unroll 8
    for (int i = 0; i < 32; ++i) {
      float4 k = Ks4[l * 32 + (i ^ (l & 7))];
      float4 q0 = *reinterpret_cast<const float4*>(q0p + 4 * i);
      float4 q1 = *reinterpret_cast<const float4*>(q1p + 4 * i);
      float4 q2 = *reinterpret_cast<const float4*>(q2p + 4 * i);
      float4 q3 = *reinterpret_cast<const float4*>(q3p + 4 * i);
      s0 += q0.x * k.x + q0.y * k.y + q0.z * k.z + q0.w * k.w;
      s1 += q1.x * k.x + q1.y * k.y + q1.z * k.z + q1.w * k.w;
      s2 += q2.x * k.x + q2.y * k.y + q2.z * k.z + q2.w * k.w;
      s3 += q3.x * k.x + q3.y * k.y + q3.z * k.z + q3.w * k.w;
    }
    s0 *= scale; s1 *= scale; s2 *= scale; s3 *= scale;

    float p0 = __expf(s0 - wave_max64(s0));
    float p1 = __expf(s1 - wave_max64(s1));
    float p2 = __expf(s2 - wave_max64(s2));
    float p3 = __expf(s3 - wave_max64(s3));
    p0 /= wave_sum64(p0); p1 /= wave_sum64(p1);
    p2 /= wave_sum64(p2); p3 /= wave_sum64(p3);

    Ps[w][0][l] = p0; Ps[w][1][l] = p1; Ps[w][2][l] = p2; Ps[w][3][l] = p3;
    __threadfence_block();

    float a00 = 0.f, a01 = 0.f, a10 = 0.f, a11 = 0.f;
    float a20 = 0.f, a21 = 0.f, a30 = 0.f, a31 = 0.f;
    for (int a = 0; a < 64; ++a) {
      float2 v = *reinterpret_cast<const float2*>(&Vs[a][2 * l]);
      float pa0 = Ps[w][0][a], pa1 = Ps[w][1][a];
      float pa2 = Ps[w][2][a], pa3 = Ps[w][3][a];
      a00 += pa0 * v.x; a01 += pa0 * v.y;
      a10 += pa1 * v.x; a11 += pa1 * v.y;
      a20 += pa2 * v.x; a21 += pa2 * v.y;
      a30 += pa3 * v.x; a31 += pa3 * v.y;
    }
    size_t row0 = (size_t)(b * APG + 4 * qq) * FEAT + 2 * l;
    float2* o0 = reinterpret_cast<float2*>(out_s + row0);
    float2* o1 = reinterpret_cast<float2*>(out_s + row0 + FEAT);
    float2* o2 = reinterpret_cast<float2*>(out_s + row0 + 2 * FEAT);
    float2* o3 = reinterpret_cast<float2*>(out_s + row0 + 3 * FEAT);
    float2 c0 = *o0; c0.x += a00; c0.y += a01; *o0 = c0;
    float2 c1 = *o1; c1.x += a10; c1.y += a11; *o1 = c1;
    float2 c2 = *o2; c2.x += a20; c2.y += a21; *o2 = c2;
    float2 c3 = *o3; c3.x += a30; c3.y += a31; *o3 = c3;
    __threadfence_block();
  }
}

// ---------------------------------------------------------------- launch
extern "C" void kernel_launch(void* const* d_in, const int* in_sizes, int n_in,
                              void* d_out, int out_size, void* d_ws, size_t ws_size,
                              hipStream_t stream) {
  const float* s_j  = (const float*)d_in[0];
  const float* v_j  = (const float*)d_in[1];
  const float* r_ij = (const float*)d_in[2];
  const int*   nbrs = (const int*)d_in[3];
  const float* W1   = (const float*)d_in[5];
  const float* b1   = (const float*)d_in[6];
  const float* W2   = (const float*)d_in[7];
  const float* b2   = (const float*)d_in[8];
  const float* Wr   = (const float*)d_in[9];
  const float* br   = (const float*)d_in[10];
  const float* Wd   = (const float*)d_in[11];
  const float* bd   = (const float*)d_in[12];

  float* out_s = (float*)d_out;
  float* out_v = out_s + (size_t)NATOMS * FEAT;

  float* qkvb = (float*)d_ws;                                   // 8192*384 f32
  float* h    = qkvb;                                           // aliases (dead early)
  ushort_t* phi_bf = (ushort_t*)(qkvb + (size_t)NATOMS * 384);  // 8192*384 bf16
  ushort_t* vbf    = phi_bf + (size_t)NATOMS * 384;             // 8192*384 bf16
  int* sorted = (int*)(vbf + (size_t)NATOMS * 384);
  int* offs   = sorted + NEDGES;
  int* cursor = offs + (NATOMS + 1);
  int* counts = cursor + NATOMS;

  zero_kernel<<<(NATOMS + 255) / 256, 256, 0, stream>>>(counts, NATOMS);
  repackv_kernel<<<NATOMS * 384 / 256, 256, 0, stream>>>(v_j, vbf);
  gemm_k128<<<dim3(NATOMS / 64, 2), 256, 0, stream>>>(s_j, W1, b1, h, nullptr, 128, 1);
  gemm_k128<<<dim3(NATOMS / 64, 6), 256, 0, stream>>>(h, W2, b2, nullptr, phi_bf, 384, 2);
  gemm_k128<<<dim3(NATOMS / 64, 6), 256, 0, stream>>>(s_j, Wd, bd, qkvb, nullptr, 384, 0);
  hist_kernel<<<NEDGES / 256, 256, 0, stream>>>(nbrs, counts);
  scan_kernel<<<1, 1024, 0, stream>>>(counts, offs, cursor);
  scatter_kernel<<<NEDGES / 256, 256, 0, stream>>>(nbrs, cursor, sorted);
  edge_mfma_kernel<<<NATOMS / 4, 256, 0, stream>>>(sorted, offs, nbrs, r_ij, phi_bf,
                                                   vbf, Wr, br, out_s, out_v);
  attn_kernel<<<NGRAPH, 256, 0, stream>>>(qkvb, out_s);
}

// Round 4
// 233.638 us; speedup vs baseline: 2.3053x; 2.3053x over previous
//
#include <hip/hip_runtime.h>
#include <hip/hip_bf16.h>
#include <cstdint>

#define FEAT    128
#define NRBF    20
#define NATOMS  8192
#define NEDGES  262144
#define NGRAPH  128
#define APG     64
#define PI_F    3.14159265358979323846f
#define CUTOFF_F 5.0f
#define ECH     6

typedef unsigned int uint_t;
typedef unsigned short ushort_t;
typedef __attribute__((ext_vector_type(2))) float f32x2;
typedef __attribute__((ext_vector_type(4))) float f32x4;
typedef __attribute__((ext_vector_type(4))) short short4v;
typedef __attribute__((ext_vector_type(8))) short short8;

#if __has_builtin(__builtin_elementwise_fma)
#define PKFMA(a, b, c) __builtin_elementwise_fma((a), (b), (c))
#else
#define PKFMA(a, b, c) ((a) * (b) + (c))
#endif

__device__ __forceinline__ float bflo(uint_t u) { return __uint_as_float(u << 16); }
__device__ __forceinline__ float bfhi(uint_t u) { return __uint_as_float(u & 0xffff0000u); }
__device__ __forceinline__ ushort_t f2bf(float f) {
  uint_t u = __float_as_uint(f);
  return (ushort_t)((u + 0x7fffu + ((u >> 16) & 1u)) >> 16);
}

// ---------------------------------------------------------------- f32 -> bf16
__global__ void tobf16_kernel(const float* __restrict__ in,
                              ushort_t* __restrict__ out, int n4) {
  int i = blockIdx.x * blockDim.x + threadIdx.x;
  if (i < n4) {
    float4 v = reinterpret_cast<const float4*>(in)[i];
    ushort4 o = {f2bf(v.x), f2bf(v.y), f2bf(v.z), f2bf(v.w)};
    reinterpret_cast<ushort4*>(out)[i] = o;
  }
}

// ------------------------------------------- W -> frag-order swizzled bf16
// out[(ks*NT+ctg)*512 + lane*8 + jj] = bf16(W[32ks + kmap(g,jj)][16ctg + q])
// kmap(g,jj) = 4g + (jj&3) + 16*(jj>>2); verified by round-3 pass.
__global__ void swzw_kernel(const float* __restrict__ W, ushort_t* __restrict__ out,
                            int N, int NT, int total) {
  int i = blockIdx.x * 256 + threadIdx.x;
  if (i >= total) return;
  int jj = i & 7, lane = (i >> 3) & 63, tile = i >> 9;
  int ks = tile / NT, ctg = tile - ks * NT;
  int g = lane >> 4, q = lane & 15;
  int k = 32 * ks + 4 * g + (jj & 3) + 16 * (jj >> 2);
  int c = 16 * ctg + q;
  out[i] = f2bf(W[(size_t)k * N + c]);
}

// ---------------------------------------------------------------- MFMA GEMM
// C[8192 x N] = act(A_bf[8192 x 128] @ W + b). Tile 64x64, 4 waves, 16 MFMA/wave.
// Fragment maps verified by round-3 pass: A lane(g,q): row=q, k=kmap(g,jj);
// B lane(g,q): col=q, k=kmap(g,jj); C: row=4g+reg, col=q.
__global__ __launch_bounds__(256) void gemm_mfma(
    const ushort_t* __restrict__ Abf, const ushort_t* __restrict__ Wswz,
    const float* __restrict__ bias, float* __restrict__ Cf,
    ushort_t* __restrict__ Cb, int N, int NT, int act_silu, int out_bf) {
  __shared__ ushort_t As[64][136];  // stride 272B: 2-way-max bank pattern
  const int t = threadIdx.x;
  const int r0 = blockIdx.x * 64, c0 = blockIdx.y * 64;
  const int w = t >> 6, l = t & 63, g = l >> 4, q = l & 15;

  // B-frags: 16 coalesced b128 loads (frag-order global layout, L2-resident)
  short8 bf[4][4];
  #pragma unroll
  for (int ks = 0; ks < 4; ++ks)
    #pragma unroll
    for (int ct = 0; ct < 4; ++ct)
      bf[ks][ct] = *reinterpret_cast<const short8*>(
          Wswz + ((size_t)(ks * NT + (c0 >> 4) + ct) * 64 + l) * 8);

  // stage A tile 64x128 bf16 (already bf16 in global)
  for (int i = t; i < 64 * 16; i += 256) {
    int r = i >> 4, g8 = i & 15;
    short8 v = *reinterpret_cast<const short8*>(Abf + (size_t)(r0 + r) * 128 + 8 * g8);
    *reinterpret_cast<short8*>(&As[r][8 * g8]) = v;
  }
  __syncthreads();

  f32x4 acc[4] = {};
  #pragma unroll
  for (int ks = 0; ks < 4; ++ks) {
    const ushort_t* ap = &As[16 * w + q][32 * ks + 4 * g];
    short4v alo = *reinterpret_cast<const short4v*>(ap);
    short4v ahi = *reinterpret_cast<const short4v*>(ap + 16);
    short8 af;
    af[0] = alo[0]; af[1] = alo[1]; af[2] = alo[2]; af[3] = alo[3];
    af[4] = ahi[0]; af[5] = ahi[1]; af[6] = ahi[2]; af[7] = ahi[3];
    #pragma unroll
    for (int ct = 0; ct < 4; ++ct)
      acc[ct] = __builtin_amdgcn_mfma_f32_16x16x32_bf16(af, bf[ks][ct], acc[ct], 0, 0, 0);
  }

  #pragma unroll
  for (int ct = 0; ct < 4; ++ct) {
    float bb = bias[c0 + 16 * ct + q];
    #pragma unroll
    for (int r = 0; r < 4; ++r) {
      float o = acc[ct][r] + bb;
      if (act_silu) o = o / (1.f + __expf(-o));
      size_t off = (size_t)(r0 + 16 * w + 4 * g + r) * N + c0 + 16 * ct + q;
      if (out_bf) Cb[off] = f2bf(o);
      else        Cf[off] = o;
    }
  }
}

// ---------------------------------------------------------------- sort helpers
__global__ void zero_kernel(int* __restrict__ p, int n) {
  int i = blockIdx.x * blockDim.x + threadIdx.x;
  if (i < n) p[i] = 0;
}

__global__ void hist_kernel(const int* __restrict__ nbrs, int* __restrict__ counts) {
  int e = blockIdx.x * blockDim.x + threadIdx.x;
  if (e < NEDGES) atomicAdd(&counts[nbrs[2 * e]], 1);
}

__global__ __launch_bounds__(1024) void scan_kernel(
    const int* __restrict__ counts, int* __restrict__ offs, int* __restrict__ cursor) {
  __shared__ int part[1024];
  const int t = threadIdx.x;
  int local[8];
  int s = 0;
  #pragma unroll
  for (int i = 0; i < 8; ++i) { local[i] = counts[t * 8 + i]; s += local[i]; }
  part[t] = s;
  __syncthreads();
  for (int off = 1; off < 1024; off <<= 1) {
    int v = part[t];
    int add = (t >= off) ? part[t - off] : 0;
    __syncthreads();
    part[t] = v + add;
    __syncthreads();
  }
  int excl = part[t] - s;
  #pragma unroll
  for (int i = 0; i < 8; ++i) {
    offs[t * 8 + i] = excl;
    cursor[t * 8 + i] = excl;
    excl += local[i];
  }
  if (t == 1023) offs[NATOMS] = excl;
}

__global__ void scatter_kernel(const int* __restrict__ nbrs, int* __restrict__ cursor,
                               int* __restrict__ sorted) {
  int e = blockIdx.x * blockDim.x + threadIdx.x;
  if (e < NEDGES) {
    int seg = nbrs[2 * e];
    int pos = atomicAdd(&cursor[seg], 1);
    sorted[pos] = e;
  }
}

// ---------------------------------------------------------------- edge accumulation
// Round-1 structure (one wave/atom, 6-edge chunks, LDS metadata) with:
//  (a) Wr as packed-bf16 pairs + pre-splatted rbf pairs -> LDS 19.7 KB (8 blocks/CU)
//  (b) chunk gathers (phi bf16, v_j f32) issued BEFORE the wsv loop
//  (c) wsv loop in f32x2 -> v_pk_fma_f32
__global__ __launch_bounds__(256) void edge_accum_kernel(
    const int* __restrict__ sorted, const int* __restrict__ offs,
    const int* __restrict__ nbrs, const float* __restrict__ r_ij,
    const ushort_t* __restrict__ phi, const float* __restrict__ v_j,
    const float* __restrict__ Wr, const float* __restrict__ br,
    float* __restrict__ out_s, float* __restrict__ out_v) {
  __shared__ uint_t sWrp[3 * NRBF * 64];   // bf16-pair packed, 15360 B
  __shared__ f32x2 eR2[4][ECH][NRBF];      // pre-splatted rbf, 3840 B
  __shared__ float eU[4][ECH][3];
  __shared__ float eE[4][ECH];
  __shared__ int   eJ[4][ECH];

  const int t = threadIdx.x;
  for (int i = t; i < 3 * NRBF * 64; i += 256) {
    int l2 = i & 63, sn = i >> 6;
    int s = sn / NRBF, n = sn - s * NRBF;
    float w0 = Wr[n * 384 + s * 128 + 2 * l2];
    float w1 = Wr[n * 384 + s * 128 + 2 * l2 + 1];
    sWrp[i] = ((uint_t)f2bf(w1) << 16) | (uint_t)f2bf(w0);
  }
  __syncthreads();

  const int w = t >> 6, l = t & 63;
  const int atom = blockIdx.x * 4 + w;
  const int start = offs[atom], end = offs[atom + 1];
  const float c1 = PI_F / CUTOFF_F;

  float2 br0 = *reinterpret_cast<const float2*>(br + 2 * l);
  float2 br1 = *reinterpret_cast<const float2*>(br + 128 + 2 * l);
  float2 br2 = *reinterpret_cast<const float2*>(br + 256 + 2 * l);

  float ds0 = 0.f, ds1 = 0.f;
  float dv00 = 0.f, dv01 = 0.f, dv02 = 0.f;
  float dv10 = 0.f, dv11 = 0.f, dv12 = 0.f;

  for (int base = start; base < end; base += ECH) {
    __threadfence_block();  // WAR: previous chunk reads done before overwrite
    #pragma unroll
    for (int rr = 0; rr < 2; ++rr) {
      int task = l + rr * 64;
      if (task < ECH * NRBF) {
        int el = task / NRBF;
        int n = task - el * NRBF;
        int eidx = base + el;
        float rbfv = 0.f;
        if (eidx < end) {
          int e = sorted[eidx];
          float x = r_ij[3 * e], y = r_ij[3 * e + 1], z = r_ij[3 * e + 2];
          float d = sqrtf(x * x + y * y + z * z);
          float env = 0.f;
          if (d < CUTOFF_F) env = 0.5f * (__cosf(c1 * d) + 1.f);
          float inv = 1.f / d;
          rbfv = __sinf((float)(n + 1) * c1 * d) * inv * env;
          if (n == 0) {
            eJ[w][el] = nbrs[2 * e + 1];
            eE[w][el] = env;
            eU[w][el][0] = x * inv;
            eU[w][el][1] = y * inv;
            eU[w][el][2] = z * inv;
          }
        } else if (n == 0) {
          eJ[w][el] = 0;
          eE[w][el] = 0.f;
          eU[w][el][0] = 0.f; eU[w][el][1] = 0.f; eU[w][el][2] = 0.f;
        }
        eR2[w][el][n] = (f32x2){rbfv, rbfv};
      }
    }
    __threadfence_block();  // setup writes visible before reads

    // ---- issue all chunk gathers up front (consumed after wsv loop)
    int jv[ECH];
    #pragma unroll
    for (int el = 0; el < ECH; ++el) jv[el] = eJ[w][el];
    uint_t pg[ECH][3];
    float2 vg[ECH][3];
    #pragma unroll
    for (int el = 0; el < ECH; ++el) {
      const ushort_t* pj = phi + (size_t)jv[el] * 384 + 2 * l;
      pg[el][0] = *reinterpret_cast<const uint_t*>(pj);
      pg[el][1] = *reinterpret_cast<const uint_t*>(pj + 128);
      pg[el][2] = *reinterpret_cast<const uint_t*>(pj + 256);
      const float* vj = v_j + (size_t)jv[el] * 384 + 6 * l;
      vg[el][0] = *reinterpret_cast<const float2*>(vj);
      vg[el][1] = *reinterpret_cast<const float2*>(vj + 2);
      vg[el][2] = *reinterpret_cast<const float2*>(vj + 4);
    }

    // ---- wsv: f32x2 packed, 3 sections x 6 edges per rbf term
    float envb[ECH];
    #pragma unroll
    for (int el = 0; el < ECH; ++el) envb[el] = eE[w][el];
    f32x2 wsv[ECH][3];
    #pragma unroll
    for (int el = 0; el < ECH; ++el) {
      wsv[el][0] = (f32x2){envb[el] * br0.x, envb[el] * br0.y};
      wsv[el][1] = (f32x2){envb[el] * br1.x, envb[el] * br1.y};
      wsv[el][2] = (f32x2){envb[el] * br2.x, envb[el] * br2.y};
    }
    #pragma unroll
    for (int n = 0; n < NRBF; ++n) {
      uint_t u0 = sWrp[(0 * NRBF + n) * 64 + l];
      uint_t u1 = sWrp[(1 * NRBF + n) * 64 + l];
      uint_t u2 = sWrp[(2 * NRBF + n) * 64 + l];
      f32x2 w0 = (f32x2){bflo(u0), bfhi(u0)};
      f32x2 w1 = (f32x2){bflo(u1), bfhi(u1)};
      f32x2 w2 = (f32x2){bflo(u2), bfhi(u2)};
      #pragma unroll
      for (int el = 0; el < ECH; ++el) {
        f32x2 rn2 = eR2[w][el][n];
        wsv[el][0] = PKFMA(rn2, w0, wsv[el][0]);
        wsv[el][1] = PKFMA(rn2, w1, wsv[el][1]);
        wsv[el][2] = PKFMA(rn2, w2, wsv[el][2]);
      }
    }

    // ---- epilogue: consume gathers
    #pragma unroll
    for (int el = 0; el < ECH; ++el) {
      float u0 = eU[w][el][0], u1 = eU[w][el][1], u2 = eU[w][el][2];
      float p00 = bflo(pg[el][0]), p01 = bfhi(pg[el][0]);
      float p10 = bflo(pg[el][1]), p11 = bfhi(pg[el][1]);
      float p20 = bflo(pg[el][2]), p21 = bfhi(pg[el][2]);
      float2 va = vg[el][0], vb = vg[el][1], vc = vg[el][2];
      float s00 = p00 * wsv[el][0].x, s01 = p01 * wsv[el][0].y;
      ds0 += p10 * wsv[el][1].x;
      ds1 += p11 * wsv[el][1].y;
      float s20 = p20 * wsv[el][2].x, s21 = p21 * wsv[el][2].y;
      dv00 += s20 * u0 + s00 * va.x;
      dv01 += s20 * u1 + s00 * va.y;
      dv02 += s20 * u2 + s00 * vb.x;
      dv10 += s21 * u0 + s01 * vb.y;
      dv11 += s21 * u1 + s01 * vc.x;
      dv12 += s21 * u2 + s01 * vc.y;
    }
  }

  *reinterpret_cast<float2*>(out_s + (size_t)atom * FEAT + 2 * l) = make_float2(ds0, ds1);
  float* ov = out_v + (size_t)atom * 384 + 6 * l;
  *reinterpret_cast<float2*>(ov)     = make_float2(dv00, dv01);
  *reinterpret_cast<float2*>(ov + 2) = make_float2(dv02, dv10);
  *reinterpret_cast<float2*>(ov + 4) = make_float2(dv11, dv12);
}

// ---------------------------------------------------------------- attention
__device__ __forceinline__ float wave_max64(float v) {
  #pragma unroll
  for (int m = 32; m > 0; m >>= 1) v = fmaxf(v, __shfl_xor(v, m, 64));
  return v;
}
__device__ __forceinline__ float wave_sum64(float v) {
  #pragma unroll
  for (int m = 32; m > 0; m >>= 1) v += __shfl_xor(v, m, 64);
  return v;
}

__global__ __launch_bounds__(256) void attn_kernel(const float* __restrict__ qkv,
                                                   float* __restrict__ out_s) {
  __shared__ float4 Ks4[64 * 32];
  __shared__ float  Vs[64][130];
  __shared__ float  Ps[4][4][64];
  const int b = blockIdx.x;
  const int t = threadIdx.x;
  const float* base = qkv + (size_t)b * APG * 384;

  for (int i = t; i < 64 * 32; i += 256) {
    int a = i >> 5, gg = i & 31;
    float4 kv = *reinterpret_cast<const float4*>(base + a * 384 + 128 + 4 * gg);
    Ks4[a * 32 + (gg ^ (a & 7))] = kv;
  }
  for (int i = t; i < 64 * 32; i += 256) {
    int a = i >> 5, gg = i & 31;
    float4 vvv = *reinterpret_cast<const float4*>(base + a * 384 + 256 + 4 * gg);
    Vs[a][4 * gg + 0] = vvv.x; Vs[a][4 * gg + 1] = vvv.y;
    Vs[a][4 * gg + 2] = vvv.z; Vs[a][4 * gg + 3] = vvv.w;
  }
  __syncthreads();

  const int w = t >> 6, l = t & 63;
  const float scale = 0.08838834764831845f;

  for (int qq = w; qq < 16; qq += 4) {
    const float* q0p = base + (size_t)(4 * qq + 0) * 384;
    const float* q1p = base + (size_t)(4 * qq + 1) * 384;
    const float* q2p = base + (size_t)(4 * qq + 2) * 384;
    const float* q3p = base + (size_t)(4 * qq + 3) * 384;
    float s0 = 0.f, s1 = 0.f, s2 = 0.f, s3 = 0.f;
    #pragma unroll 8
    for (int i = 0; i < 32; ++i) {
      float4 k = Ks4[l * 32 + (i ^ (l & 7))];
      float4 q0 = *reinterpret_cast<const float4*>(q0p + 4 * i);
      float4 q1 = *reinterpret_cast<const float4*>(q1p + 4 * i);
      float4 q2 = *reinterpret_cast<const float4*>(q2p + 4 * i);
      float4 q3 = *reinterpret_cast<const float4*>(q3p + 4 * i);
      s0 += q0.x * k.x + q0.y * k.y + q0.z * k.z + q0.w * k.w;
      s1 += q1.x * k.x + q1.y * k.y + q1.z * k.z + q1.w * k.w;
      s2 += q2.x * k.x + q2.y * k.y + q2.z * k.z + q2.w * k.w;
      s3 += q3.x * k.x + q3.y * k.y + q3.z * k.z + q3.w * k.w;
    }
    s0 *= scale; s1 *= scale; s2 *= scale; s3 *= scale;

    float p0 = __expf(s0 - wave_max64(s0));
    float p1 = __expf(s1 - wave_max64(s1));
    float p2 = __expf(s2 - wave_max64(s2));
    float p3 = __expf(s3 - wave_max64(s3));
    p0 /= wave_sum64(p0); p1 /= wave_sum64(p1);
    p2 /= wave_sum64(p2); p3 /= wave_sum64(p3);

    Ps[w][0][l] = p0; Ps[w][1][l] = p1; Ps[w][2][l] = p2; Ps[w][3][l] = p3;
    __threadfence_block();

    float a00 = 0.f, a01 = 0.f, a10 = 0.f, a11 = 0.f;
    float a20 = 0.f, a21 = 0.f, a30 = 0.f, a31 = 0.f;
    for (int a = 0; a < 64; ++a) {
      float2 v = *reinterpret_cast<const float2*>(&Vs[a][2 * l]);
      float pa0 = Ps[w][0][a], pa1 = Ps[w][1][a];
      float pa2 = Ps[w][2][a], pa3 = Ps[w][3][a];
      a00 += pa0 * v.x; a01 += pa0 * v.y;
      a10 += pa1 * v.x; a11 += pa1 * v.y;
      a20 += pa2 * v.x; a21 += pa2 * v.y;
      a30 += pa3 * v.x; a31 += pa3 * v.y;
    }
    size_t row0 = (size_t)(b * APG + 4 * qq) * FEAT + 2 * l;
    float2* o0 = reinterpret_cast<float2*>(out_s + row0);
    float2* o1 = reinterpret_cast<float2*>(out_s + row0 + FEAT);
    float2* o2 = reinterpret_cast<float2*>(out_s + row0 + 2 * FEAT);
    float2* o3 = reinterpret_cast<float2*>(out_s + row0 + 3 * FEAT);
    float2 c0 = *o0; c0.x += a00; c0.y += a01; *o0 = c0;
    float2 c1 = *o1; c1.x += a10; c1.y += a11; *o1 = c1;
    float2 c2 = *o2; c2.x += a20; c2.y += a21; *o2 = c2;
    float2 c3 = *o3; c3.x += a30; c3.y += a31; *o3 = c3;
    __threadfence_block();
  }
}

// ---------------------------------------------------------------- launch
extern "C" void kernel_launch(void* const* d_in, const int* in_sizes, int n_in,
                              void* d_out, int out_size, void* d_ws, size_t ws_size,
                              hipStream_t stream) {
  const float* s_j  = (const float*)d_in[0];
  const float* v_j  = (const float*)d_in[1];
  const float* r_ij = (const float*)d_in[2];
  const int*   nbrs = (const int*)d_in[3];
  const float* W1   = (const float*)d_in[5];
  const float* b1   = (const float*)d_in[6];
  const float* W2   = (const float*)d_in[7];
  const float* b2   = (const float*)d_in[8];
  const float* Wr   = (const float*)d_in[9];
  const float* br   = (const float*)d_in[10];
  const float* Wd   = (const float*)d_in[11];
  const float* bd   = (const float*)d_in[12];

  float* out_s = (float*)d_out;
  float* out_v = out_s + (size_t)NATOMS * FEAT;

  // workspace layout (23.3 MB total; sort buffers alias dead h_bf)
  float*    qkvb   = (float*)d_ws;                                   // 12.58 MB f32
  ushort_t* phi_bf = (ushort_t*)(qkvb + (size_t)NATOMS * 384);       // 6.29 MB bf16
  ushort_t* s_bf   = phi_bf + (size_t)NATOMS * 384;                  // 2.10 MB bf16
  ushort_t* wswz1  = s_bf + (size_t)NATOMS * FEAT;                   // 16384 bf16
  ushort_t* wswz2  = wswz1 + 16384;                                  // 49152 bf16
  ushort_t* wswzd  = wswz2 + 49152;                                  // 49152 bf16
  ushort_t* h_bf   = wswzd + 49152;                                  // 2.10 MB (dead after GEMM2)
  int* sorted = (int*)h_bf;                                          // alias (after GEMM3)
  int* offs   = sorted + NEDGES;
  int* cursor = offs + (NATOMS + 1);
  int* counts = cursor + NATOMS;

  tobf16_kernel<<<(NATOMS * FEAT / 4 + 255) / 256, 256, 0, stream>>>(
      s_j, s_bf, NATOMS * FEAT / 4);
  swzw_kernel<<<(16384 + 255) / 256, 256, 0, stream>>>(W1, wswz1, 128, 8, 16384);
  swzw_kernel<<<(49152 + 255) / 256, 256, 0, stream>>>(W2, wswz2, 384, 24, 49152);
  swzw_kernel<<<(49152 + 255) / 256, 256, 0, stream>>>(Wd, wswzd, 384, 24, 49152);

  gemm_mfma<<<dim3(NATOMS / 64, 2), 256, 0, stream>>>(
      s_bf, wswz1, b1, nullptr, h_bf, 128, 8, 1, 1);
  gemm_mfma<<<dim3(NATOMS / 64, 6), 256, 0, stream>>>(
      h_bf, wswz2, b2, nullptr, phi_bf, 384, 24, 0, 1);
  gemm_mfma<<<dim3(NATOMS / 64, 6), 256, 0, stream>>>(
      s_bf, wswzd, bd, qkvb, nullptr, 384, 24, 0, 0);

  zero_kernel<<<(NATOMS + 255) / 256, 256, 0, stream>>>(counts, NATOMS);
  hist_kernel<<<NEDGES / 256, 256, 0, stream>>>(nbrs, counts);
  scan_kernel<<<1, 1024, 0, stream>>>(counts, offs, cursor);
  scatter_kernel<<<NEDGES / 256, 256, 0, stream>>>(nbrs, cursor, sorted);

  edge_accum_kernel<<<NATOMS / 4, 256, 0, stream>>>(sorted, offs, nbrs, r_ij, phi_bf,
                                                    v_j, Wr, br, out_s, out_v);
  attn_kernel<<<NGRAPH, 256, 0, stream>>>(qkvb, out_s);
}